// Round 18
// baseline (181.698 us; speedup 1.0000x reference)
//
#include <hip/hip_runtime.h>
#include <hip/hip_bf16.h>
#include <math.h>

typedef __attribute__((ext_vector_type(8))) __bf16 bf16x8;
typedef __attribute__((ext_vector_type(4))) __bf16 bf16x4;
typedef __attribute__((ext_vector_type(4))) float f32x4;

#define B_ 4
#define T_ 2048
#define C_ 1024
#define H_ 16
#define D_ 64
#define M_TOT (B_*T_)

static __device__ __forceinline__ f32x4 mfma_bf16(bf16x8 a, bf16x8 b, f32x4 c) {
  return __builtin_amdgcn_mfma_f32_16x16x32_bf16(a, b, c, 0, 0, 0);
}

static __device__ __forceinline__ void gload_lds16(const void* g, void* l) {
  __builtin_amdgcn_global_load_lds((const __attribute__((address_space(1))) void*)g,
                                   (__attribute__((address_space(3))) void*)l, 16, 0, 0);
}

// ---------------- fused prep: convert + rope tables + both weight transposes -------
__global__ void prep_all(const float* __restrict__ x, __bf16* __restrict__ xb,
                         float* __restrict__ cosT, float* __restrict__ sinT,
                         const float* __restrict__ Wqkv, __bf16* __restrict__ wqkvT,
                         const float* __restrict__ Wout, __bf16* __restrict__ woutT) {
  __shared__ float tile[32][33];
  const int bid = blockIdx.x;
  if (bid < 8192) {
    int i = bid * 256 + threadIdx.x;       // n4 = M_TOT*C_/4 = 2097152 = 8192*256
    float4 v = ((const float4*)x)[i];
    bf16x4 o = { (__bf16)v.x, (__bf16)v.y, (__bf16)v.z, (__bf16)v.w };
    *(bf16x4*)(xb + (size_t)i*4) = o;
  } else if (bid < 8448) {
    int idx = (bid - 8192) * 256 + threadIdx.x;   // T_*32 = 65536 = 256*256
    int t = idx >> 5, d = idx & 31;
    float inv = powf(10000.0f, -((float)(2*d)) / 64.0f);
    float ang = (float)t * inv;
    cosT[idx] = cosf(ang);
    sinT[idx] = sinf(ang);
  } else {
    int tId = bid - 8448;
    const float* in;  __bf16* out;  int N, n0, k0;
    if (tId < 3072) { in = Wqkv; out = wqkvT; N = 3072; n0 = (tId % 96)*32; k0 = (tId / 96)*32; }
    else { tId -= 3072; in = Wout; out = woutT; N = 1024; n0 = (tId % 32)*32; k0 = (tId / 32)*32; }
    int tx = threadIdx.x & 31, ty = threadIdx.x >> 5;
    #pragma unroll
    for (int r = ty; r < 32; r += 8) tile[r][tx] = in[(size_t)(k0 + r)*N + n0 + tx];
    __syncthreads();
    #pragma unroll
    for (int r = ty; r < 32; r += 8) out[(size_t)(n0 + r)*1024 + k0 + tx] = (__bf16)tile[tx][r];
  }
}

// ---------------- fine-phase pipelined GEMM: 128x256 tile, BK=64, 8 waves -----------
// Round-8 proven structure: M-banded XCD mapping, 4 phases per 2-K-tile iteration,
// counted vmcnt(4), raw s_barrier. V^T written from the epilogue via per-wave
// transpose buffers (pad 65: row stride 130B kills the 8-way column-read conflict).

#define GEMM_PHASES(N_TILES)                                                     \
  auto RD_BFR = [&](const char* lb, bf16x8 (*bfr)[2]) {                          \
    _Pragma("unroll")                                                            \
    for (int n = 0; n < 4; ++n) {                                                \
      const int row = wc*64 + n*16 + l15;                                        \
      const int sw = (row & 7) << 4;                                             \
      _Pragma("unroll")                                                          \
      for (int ks = 0; ks < 2; ++ks)                                             \
        bfr[n][ks] = *(const bf16x8*)(lb + row*128 + ((ks*64 + lhi*16) ^ sw));   \
    }                                                                            \
  };                                                                             \
  auto RD_AF = [&](const char* la, int mb, bf16x8 (*af)[2]) {                    \
    _Pragma("unroll")                                                            \
    for (int mm = 0; mm < 2; ++mm) {                                             \
      const int row = wr*64 + (mb + mm)*16 + l15;                                \
      const int sw = (row & 7) << 4;                                             \
      _Pragma("unroll")                                                          \
      for (int ks = 0; ks < 2; ++ks)                                             \
        af[mm][ks] = *(const bf16x8*)(la + row*128 + ((ks*64 + lhi*16) ^ sw));   \
    }                                                                            \
  };                                                                             \
  auto MFMA16 = [&](bf16x8 (*af)[2], bf16x8 (*bfr)[2], int mb) {                 \
    __builtin_amdgcn_s_setprio(1);                                               \
    _Pragma("unroll")                                                            \
    for (int mm = 0; mm < 2; ++mm)                                               \
      _Pragma("unroll")                                                          \
      for (int n = 0; n < 4; ++n)                                                \
        _Pragma("unroll")                                                        \
        for (int ks = 0; ks < 2; ++ks)                                           \
          acc[mb + mm][n] = mfma_bf16(af[mm][ks], bfr[n][ks], acc[mb + mm][n]);  \
    __builtin_amdgcn_s_setprio(0);                                               \
  };                                                                             \
  STAGE_B(0, (char*)lB[0]); STAGE_A(0, (char*)lA[0]); STAGE_B(1, (char*)lB[1]);  \
  asm volatile("s_waitcnt vmcnt(4)" ::: "memory");                               \
  __builtin_amdgcn_s_barrier();                                                  \
  _Pragma("unroll")                                                              \
  for (int it = 0; it < (N_TILES)/2; ++it) {                                     \
    const int t0 = it*2;                                                         \
    bf16x8 bfr[4][2], af[2][2];                                                  \
    RD_BFR((const char*)lB[0], bfr);                                             \
    RD_AF((const char*)lA[0], 0, af);                                            \
    STAGE_A(t0 + 1, (char*)lA[1]);                                               \
    __builtin_amdgcn_s_barrier();                                                \
    MFMA16(af, bfr, 0);                                                          \
    __builtin_amdgcn_s_barrier();                                                \
    RD_AF((const char*)lA[0], 2, af);                                            \
    if (t0 + 2 < (N_TILES)) STAGE_B(t0 + 2, (char*)lB[0]);                       \
    __builtin_amdgcn_s_barrier();                                                \
    MFMA16(af, bfr, 2);                                                          \
    if (t0 + 2 < (N_TILES)) asm volatile("s_waitcnt vmcnt(4)" ::: "memory");     \
    else                    asm volatile("s_waitcnt vmcnt(0)" ::: "memory");     \
    __builtin_amdgcn_s_barrier();                                                \
    RD_BFR((const char*)lB[1], bfr);                                             \
    RD_AF((const char*)lA[1], 0, af);                                            \
    if (t0 + 2 < (N_TILES)) STAGE_A(t0 + 2, (char*)lA[0]);                       \
    __builtin_amdgcn_s_barrier();                                                \
    MFMA16(af, bfr, 0);                                                          \
    __builtin_amdgcn_s_barrier();                                                \
    RD_AF((const char*)lA[1], 2, af);                                            \
    if (t0 + 3 < (N_TILES)) STAGE_B(t0 + 3, (char*)lB[1]);                       \
    __builtin_amdgcn_s_barrier();                                                \
    MFMA16(af, bfr, 2);                                                          \
    if (it < (N_TILES)/2 - 1) asm volatile("s_waitcnt vmcnt(4)" ::: "memory");   \
    __builtin_amdgcn_s_barrier();                                                \
  }

__global__ void __launch_bounds__(512, 2)
gemm_qkv_p(const __bf16* __restrict__ A, const __bf16* __restrict__ Bt,
           __bf16* __restrict__ qout, __bf16* __restrict__ kout, __bf16* __restrict__ vtout,
           const float* __restrict__ cosT, const float* __restrict__ sinT)
{
  __shared__ __attribute__((aligned(16))) char smem[98304];     // 96 KB pool
  auto lA = (__bf16 (*)[128*64])smem;                           // 2 x 16 KB
  auto lB = (__bf16 (*)[256*64])(smem + 32768);                 // 2 x 32 KB
  const int tid = threadIdx.x;
  const int lane = tid & 63, wave = tid >> 6;
  const int wr = wave >> 2, wc = wave & 3;       // 2M x 4N wave grid
  const int l15 = lane & 15, lhi = lane >> 4;

  // M-banded XCD mapping: xcd owns 8 contiguous M-tiles, sweeps N
  const int id = blockIdx.x;                 // 768 blocks
  const int xcd = id & 7, j = id >> 3;       // j in [0,96)
  const int rowt = xcd*8 + (j & 7);          // [0,64)
  const int row0 = rowt * 128;
  const int col0 = (j >> 3) * 256;           // [0,12) * 256

  f32x4 acc[4][4] = {};

  const char* Abase = (const char*)A + (size_t)row0 * 2048;   // K=1024, 2048 B/row
  const char* Bbase = (const char*)Bt + (size_t)col0 * 2048;

  auto STAGE_A = [&](int kt, char* dst) {
    #pragma unroll
    for (int c = 0; c < 2; ++c) {            // A: 128 rows x 128 B = 16 KB
      const int L = tid*16 + c*8192;
      const int row = L >> 7, colb = L & 127;
      const int sb = colb ^ ((row & 7) << 4);   // inverse swizzle on global source
      gload_lds16(Abase + (size_t)row*2048 + kt*128 + sb, dst + L);
    }
  };
  auto STAGE_B = [&](int kt, char* dst) {
    #pragma unroll
    for (int c = 0; c < 4; ++c) {            // B: 256 rows x 128 B = 32 KB
      const int L = tid*16 + c*8192;
      const int row = L >> 7, colb = L & 127;
      const int sb = colb ^ ((row & 7) << 4);
      gload_lds16(Bbase + (size_t)row*2048 + kt*128 + sb, dst + L);
    }
  };

  GEMM_PHASES(16)

  // epilogue: RoPE on q,k (scatter to (B,H,T,D)); V written TRANSPOSED ([bh][d][t]).
  const int slot = (col0 >> 6) + wc;         // 0..47
  const int which = slot >> 4;               // 0=q 1=k 2=v
  const int h = slot & 15;
  if (which == 2) {
    __bf16* lTw = (__bf16*)(smem + wave*8320);   // 64*65*2 B each, 8*8320=66560<=98304
    #pragma unroll
    for (int m = 0; m < 4; ++m)
      #pragma unroll
      for (int r = 0; r < 4; ++r) {
        const int trow = m*16 + lhi*4 + r;   // local t in [0,64)
        #pragma unroll
        for (int n = 0; n < 4; ++n)
          lTw[trow*65 + n*16 + l15] = (__bf16)acc[m][n][r];
      }
    const int t0w = row0 + wr*64;
    const int b = t0w >> 11, tloc = t0w & 2047;
    __bf16* dstv = vtout + ((size_t)(b*H_ + h)*D_)*T_;
    #pragma unroll
    for (int c2 = 0; c2 < 8; ++c2) {
      const int idx = lane + c2*64;
      const int d = idx >> 3, t8 = (idx & 7)*8;
      bf16x8 ov;
      #pragma unroll
      for (int jj = 0; jj < 8; ++jj) ov[jj] = lTw[(t8 + jj)*65 + d];
      *(bf16x8*)(dstv + (size_t)d*T_ + tloc + t8) = ov;
    }
  } else {
    __bf16* dst = (which == 0) ? qout : kout;
    const float fsc = (which == 0) ? 0.18033688011112042f : 1.0f;
    #pragma unroll
    for (int m = 0; m < 4; ++m) {
      #pragma unroll
      for (int r = 0; r < 4; ++r) {
        const int grow = row0 + wr*64 + m*16 + lhi*4 + r;
        const int b = grow >> 11, t = grow & 2047;
        const size_t obase = ((size_t)(b*H_ + h)*T_ + t)*D_;
        #pragma unroll
        for (int n = 0; n < 2; ++n) {
          const int d1 = n*16 + l15;            // [0,32)
          const float c = cosT[t*32 + d1];
          const float s = sinT[t*32 + d1];
          const float x1 = acc[m][n][r];
          const float x2 = acc[m][n+2][r];
          dst[obase + d1]      = (__bf16)((x1*c - x2*s) * fsc);
          dst[obase + d1 + 32] = (__bf16)((x1*s + x2*c) * fsc);
        }
      }
    }
  }
}

// out-proj: same fine-phase structure + M-banded XCD mapping. Grid 256 = 1 round.
__global__ void __launch_bounds__(512, 2)
gemm_out_p(const __bf16* __restrict__ A, const __bf16* __restrict__ Bt,
           float* __restrict__ fout, const float* __restrict__ bias)
{
  __shared__ __attribute__((aligned(16))) __bf16 lA[2][128*64];
  __shared__ __attribute__((aligned(16))) __bf16 lB[2][256*64];
  const int tid = threadIdx.x;
  const int lane = tid & 63, wave = tid >> 6;
  const int wr = wave >> 2, wc = wave & 3;
  const int l15 = lane & 15, lhi = lane >> 4;

  const int id = blockIdx.x;                 // 256 blocks
  const int xcd = id & 7, j = id >> 3;       // j in [0,32)
  const int rowt = xcd*8 + (j & 7);          // [0,64)
  const int row0 = rowt * 128;
  const int col0 = (j >> 3) * 256;           // [0,4) * 256

  f32x4 acc[4][4] = {};

  const char* Abase = (const char*)A + (size_t)row0 * 2048;
  const char* Bbase = (const char*)Bt + (size_t)col0 * 2048;

  auto STAGE_A = [&](int kt, char* dst) {
    #pragma unroll
    for (int c = 0; c < 2; ++c) {
      const int L = tid*16 + c*8192;
      const int row = L >> 7, colb = L & 127;
      const int sb = colb ^ ((row & 7) << 4);
      gload_lds16(Abase + (size_t)row*2048 + kt*128 + sb, dst + L);
    }
  };
  auto STAGE_B = [&](int kt, char* dst) {
    #pragma unroll
    for (int c = 0; c < 4; ++c) {
      const int L = tid*16 + c*8192;
      const int row = L >> 7, colb = L & 127;
      const int sb = colb ^ ((row & 7) << 4);
      gload_lds16(Bbase + (size_t)row*2048 + kt*128 + sb, dst + L);
    }
  };

  GEMM_PHASES(16)

  #pragma unroll
  for (int m = 0; m < 4; ++m) {
    #pragma unroll
    for (int r = 0; r < 4; ++r) {
      const int grow = row0 + wr*64 + m*16 + lhi*4 + r;
      #pragma unroll
      for (int n = 0; n < 4; ++n) {
        const int gcol = col0 + wc*64 + n*16 + l15;
        fout[(size_t)grow*1024 + gcol] = acc[m][n][r] + bias[gcol];
      }
    }
  }
}

// ---------------- flash attention: NO-SPLIT LPT, Q-in-regs, 3 blocks/CU -----------
// Round-18: lP rows padded 128 -> 136 B (68 bf16). 128-B rows = exactly 32 banks
// made bank = f(offset only): lanes {(s,lhi),(s^1,lhi^2)} structurally 4-way
// collided on every b64 P write (2.16M conflict cycles). 136 B rotates banks by
// 2/row -> the 4 colliding lanes land on banks 2s, 2s+16, 2s+-2, 2s+-2+16 (all
// distinct). lP is ds-only scratch (no gload_lds) so padding is legal.
#define THR_LOG2 8.0f
#define PSTRIDE 136

__global__ void __launch_bounds__(256, 3)
attn_kernel(const __bf16* __restrict__ q, const __bf16* __restrict__ k,
            const __bf16* __restrict__ vt, const int* __restrict__ amask,
            __bf16* __restrict__ aout)
{
  __shared__ __attribute__((aligned(16))) __bf16 lK[64*64];    // 8 KB
  __shared__ __attribute__((aligned(16))) __bf16 lVt[64*64];   // 8 KB
  __shared__ __attribute__((aligned(16))) __bf16 lP[4][32*68]; // 17 KB (padded rows)
  const int tid = threadIdx.x;
  const int lane = tid & 63, wave = tid >> 6;
  const int l15 = lane & 15, lhi = lane >> 4;

  // heavy-first LPT: blocks 0..63 -> qblock 15 (32 iters), ...
  const int qblock = 15 - (blockIdx.x >> 6);
  const int bh = blockIdx.x & 63;
  const int kbend = 2*qblock + 2;

  const int b = bh >> 4, h = bh & 15;
  const size_t kvbase = (size_t)bh * T_ * D_;
  const char* kbase  = (const char*)(k + kvbase);
  const char* vtbase = (const char*)(vt + kvbase);
  char* lPw = (char*)lP[wave];

  const int q0w = qblock*128 + wave*32;

  // Q fragments in registers (round-0 proven layout)
  bf16x8 aq[2][2];
  #pragma unroll
  for (int m = 0; m < 2; ++m)
    #pragma unroll
    for (int ks = 0; ks < 2; ++ks)
      aq[m][ks] = *(const bf16x8*)(q + kvbase + (size_t)(q0w + m*16 + l15)*D_ + ks*32 + lhi*8);

  f32x4 acc_o[2][4] = {};
  f32x4 acc_l[2] = {};
  float m_w = -3e37f;

  for (int kb = 0; kb < kbend; ++kb) {
    #pragma unroll
    for (int c = 0; c < 2; ++c) {
      const int L = tid*16 + c*4096;
      const int row = L >> 7;
      const int sb  = (L & 127) ^ ((row & 7) << 4);
      gload_lds16(kbase  + (size_t)(kb*64 + row)*128 + sb, (char*)lK + L);
      gload_lds16(vtbase + (size_t)row*(T_*2) + (size_t)kb*128 + sb, (char*)lVt + L);
    }
    __syncthreads();

    if (kb*64 <= q0w + 31) {
      const char* lKc = (const char*)lK;
      const char* lVc = (const char*)lVt;

      // pad-mask bits for this k-tile: bit i = amask[kb*64+i] != 0
      const unsigned long long pm = __ballot(amask[b*T_ + kb*64 + lane] != 0);

      // SWAPPED QK^T: sc[m][n] = mfma(K_frag, Q_frag)
      //   value S[q][k]: q = q0w + m*16 + l15 ; k = kb*64 + n*16 + lhi*4 + r
      f32x4 sc[2][4] = {};
      __builtin_amdgcn_s_setprio(1);
      #pragma unroll
      for (int n = 0; n < 4; ++n) {
        const int row = n*16 + l15;
        const int sw = (row & 7) << 4;
        #pragma unroll
        for (int ks = 0; ks < 2; ++ks) {
          bf16x8 bk = *(const bf16x8*)(lKc + row*128 + ((ks*64 + lhi*16) ^ sw));
          #pragma unroll
          for (int m = 0; m < 2; ++m)
            sc[m][n] = mfma_bf16(bk, aq[m][ks], sc[m][n]);
        }
      }
      __builtin_amdgcn_s_setprio(0);

      // causal mask (swapped indices)
      if (kb*64 + 63 > q0w) {
        #pragma unroll
        for (int m = 0; m < 2; ++m) {
          const int qv = q0w + m*16 + l15;
          #pragma unroll
          for (int n = 0; n < 4; ++n)
            #pragma unroll
            for (int r = 0; r < 4; ++r)
              if (kb*64 + n*16 + lhi*4 + r > qv) sc[m][n][r] = -3e37f;
        }
      }

      f32x4 vm = sc[0][0];
      #pragma unroll
      for (int m = 0; m < 2; ++m)
        #pragma unroll
        for (int n = 0; n < 4; ++n) {
          if (m == 0 && n == 0) continue;
          #pragma unroll
          for (int r = 0; r < 4; ++r) vm[r] = fmaxf(vm[r], sc[m][n][r]);
        }
      float tmax = fmaxf(fmaxf(vm[0], vm[1]), fmaxf(vm[2], vm[3]));
      #pragma unroll
      for (int off = 1; off < 64; off <<= 1)
        tmax = fmaxf(tmax, __shfl_xor(tmax, off));

      if (tmax > m_w + THR_LOG2) {
        const float corr = __builtin_amdgcn_exp2f(m_w - tmax);
        #pragma unroll
        for (int m = 0; m < 2; ++m) {
          #pragma unroll
          for (int c = 0; c < 4; ++c) acc_o[m][c] *= corr;
          acc_l[m] *= corr;
        }
        m_w = tmax;
      }

      // P pack + vector write: row = m*16 + l15 (q-row), 4 contiguous k per (n)
      const int swq = (l15 & 7) << 4;
      if (pm == ~0ull) {
        // fast path: all k valid -> subtrahend is m_w everywhere
        #pragma unroll
        for (int m = 0; m < 2; ++m) {
          char* prow = lPw + (m*16 + l15)*PSTRIDE;
          #pragma unroll
          for (int n = 0; n < 4; ++n) {
            bf16x4 pk;
            #pragma unroll
            for (int r = 0; r < 4; ++r)
              pk[r] = (__bf16)__builtin_amdgcn_exp2f(sc[m][n][r] - m_w);
            *(bf16x4*)(prow + ((32*n + 8*lhi) ^ swq)) = pk;
          }
        }
      } else {
        #pragma unroll
        for (int m = 0; m < 2; ++m) {
          char* prow = lPw + (m*16 + l15)*PSTRIDE;
          #pragma unroll
          for (int n = 0; n < 4; ++n) {
            bf16x4 pk;
            #pragma unroll
            for (int r = 0; r < 4; ++r) {
              const float sub = ((pm >> (n*16 + lhi*4 + r)) & 1) ? m_w : 3e37f;
              pk[r] = (__bf16)__builtin_amdgcn_exp2f(sc[m][n][r] - sub);
            }
            *(bf16x4*)(prow + ((32*n + 8*lhi) ^ swq)) = pk;
          }
        }
      }

      bf16x8 pa[2][2];
      #pragma unroll
      for (int m = 0; m < 2; ++m) {
        const int row = m*16 + l15;
        const int sw = (row & 7) << 4;
        #pragma unroll
        for (int ks = 0; ks < 2; ++ks)
          pa[m][ks] = *(const bf16x8*)(lPw + row*PSTRIDE + ((ks*64 + lhi*16) ^ sw));
      }

      __builtin_amdgcn_s_setprio(1);
      const __bf16 one = (__bf16)1.0f;
      const bf16x8 vone = {one, one, one, one, one, one, one, one};
      #pragma unroll
      for (int m = 0; m < 2; ++m)
        #pragma unroll
        for (int ks = 0; ks < 2; ++ks)
          acc_l[m] = mfma_bf16(pa[m][ks], vone, acc_l[m]);

      #pragma unroll
      for (int c = 0; c < 4; ++c) {
        const int row = c*16 + l15;
        const int sw = (row & 7) << 4;
        #pragma unroll
        for (int ks = 0; ks < 2; ++ks) {
          bf16x8 bv = *(const bf16x8*)(lVc + row*128 + ((ks*64 + lhi*16) ^ sw));
          #pragma unroll
          for (int m = 0; m < 2; ++m)
            acc_o[m][c] = mfma_bf16(pa[m][ks], bv, acc_o[m][c]);
        }
      }
      __builtin_amdgcn_s_setprio(0);
    }
    __syncthreads();
  }

  // normalize and write
  #pragma unroll
  for (int m = 0; m < 2; ++m)
    #pragma unroll
    for (int r = 0; r < 4; ++r) {
      const int tq = q0w + m*16 + lhi*4 + r;
      const float invl = 1.0f / acc_l[m][r];
      const size_t obase = ((size_t)b*T_ + tq)*C_ + h*D_;
      #pragma unroll
      for (int c = 0; c < 4; ++c)
        aout[obase + c*16 + l15] = (__bf16)(acc_o[m][c][r] * invl);
    }
}

// ---------------- launch ----------------

extern "C" void kernel_launch(void* const* d_in, const int* in_sizes, int n_in,
                              void* d_out, int out_size, void* d_ws, size_t ws_size,
                              hipStream_t stream)
{
  const float* x     = (const float*)d_in[0];
  const int*   amask = (const int*)d_in[1];
  const float* Wqkv  = (const float*)d_in[2];
  const float* Wout  = (const float*)d_in[3];
  const float* bout  = (const float*)d_in[4];
  float* out = (float*)d_out;

  char* w = (char*)d_ws;
  __bf16* xb    = (__bf16*)w;  w += (size_t)M_TOT*C_*2;       // 16 MB
  __bf16* wqkvT = (__bf16*)w;  w += (size_t)3072*1024*2;      // 6 MB
  __bf16* woutT = (__bf16*)w;  w += (size_t)1024*1024*2;      // 2 MB
  __bf16* qb    = (__bf16*)w;  w += (size_t)B_*H_*T_*D_*2;    // 16 MB
  __bf16* kb    = (__bf16*)w;  w += (size_t)B_*H_*T_*D_*2;    // 16 MB
  __bf16* vtb   = (__bf16*)w;  w += (size_t)B_*H_*T_*D_*2;    // 16 MB  (V^T, written by gemm)
  __bf16* aob   = (__bf16*)w;  w += (size_t)M_TOT*C_*2;       // 16 MB
  float*  cosT  = (float*)w;   w += (size_t)T_*32*4;
  float*  sinT  = (float*)w;   w += (size_t)T_*32*4;

  prep_all<<<dim3(8192 + 256 + 3072 + 1024), 256, 0, stream>>>(
      x, xb, cosT, sinT, Wqkv, wqkvT, Wout, woutT);

  gemm_qkv_p<<<dim3(768), 512, 0, stream>>>(xb, wqkvT, qb, kb, vtb, cosT, sinT);

  attn_kernel<<<dim3(1024), 256, 0, stream>>>(qb, kb, vtb, amask, aob);

  gemm_out_p<<<dim3(256), 512, 0, stream>>>(aob, woutT, out, bout);
}

// Round 19
// 163.547 us; speedup vs baseline: 1.1110x; 1.1110x over previous
//
#include <hip/hip_runtime.h>
#include <hip/hip_bf16.h>
#include <math.h>

typedef __attribute__((ext_vector_type(8))) __bf16 bf16x8;
typedef __attribute__((ext_vector_type(4))) __bf16 bf16x4;
typedef __attribute__((ext_vector_type(4))) float f32x4;

#define B_ 4
#define T_ 2048
#define C_ 1024
#define H_ 16
#define D_ 64
#define M_TOT (B_*T_)

static __device__ __forceinline__ f32x4 mfma_bf16(bf16x8 a, bf16x8 b, f32x4 c) {
  return __builtin_amdgcn_mfma_f32_16x16x32_bf16(a, b, c, 0, 0, 0);
}

static __device__ __forceinline__ void gload_lds16(const void* g, void* l) {
  __builtin_amdgcn_global_load_lds((const __attribute__((address_space(1))) void*)g,
                                   (__attribute__((address_space(3))) void*)l, 16, 0, 0);
}

// ---------------- fused prep: convert + rope tables + both weight transposes -------
__global__ void prep_all(const float* __restrict__ x, __bf16* __restrict__ xb,
                         float* __restrict__ cosT, float* __restrict__ sinT,
                         const float* __restrict__ Wqkv, __bf16* __restrict__ wqkvT,
                         const float* __restrict__ Wout, __bf16* __restrict__ woutT) {
  __shared__ float tile[32][33];
  const int bid = blockIdx.x;
  if (bid < 8192) {
    int i = bid * 256 + threadIdx.x;       // n4 = M_TOT*C_/4 = 2097152 = 8192*256
    float4 v = ((const float4*)x)[i];
    bf16x4 o = { (__bf16)v.x, (__bf16)v.y, (__bf16)v.z, (__bf16)v.w };
    *(bf16x4*)(xb + (size_t)i*4) = o;
  } else if (bid < 8448) {
    int idx = (bid - 8192) * 256 + threadIdx.x;   // T_*32 = 65536 = 256*256
    int t = idx >> 5, d = idx & 31;
    float inv = powf(10000.0f, -((float)(2*d)) / 64.0f);
    float ang = (float)t * inv;
    cosT[idx] = cosf(ang);
    sinT[idx] = sinf(ang);
  } else {
    int tId = bid - 8448;
    const float* in;  __bf16* out;  int N, n0, k0;
    if (tId < 3072) { in = Wqkv; out = wqkvT; N = 3072; n0 = (tId % 96)*32; k0 = (tId / 96)*32; }
    else { tId -= 3072; in = Wout; out = woutT; N = 1024; n0 = (tId % 32)*32; k0 = (tId / 32)*32; }
    int tx = threadIdx.x & 31, ty = threadIdx.x >> 5;
    #pragma unroll
    for (int r = ty; r < 32; r += 8) tile[r][tx] = in[(size_t)(k0 + r)*N + n0 + tx];
    __syncthreads();
    #pragma unroll
    for (int r = ty; r < 32; r += 8) out[(size_t)(n0 + r)*1024 + k0 + tx] = (__bf16)tile[tx][r];
  }
}

// ---------------- fine-phase pipelined GEMM: 128x256 tile, BK=64, 8 waves -----------
// Round-8 proven structure: M-banded XCD mapping, 4 phases per 2-K-tile iteration,
// counted vmcnt(4), raw s_barrier. V^T written from the epilogue via per-wave
// transpose buffers (pad 65: row stride 130B kills the 8-way column-read conflict).

#define GEMM_PHASES(N_TILES)                                                     \
  auto RD_BFR = [&](const char* lb, bf16x8 (*bfr)[2]) {                          \
    _Pragma("unroll")                                                            \
    for (int n = 0; n < 4; ++n) {                                                \
      const int row = wc*64 + n*16 + l15;                                        \
      const int sw = (row & 7) << 4;                                             \
      _Pragma("unroll")                                                          \
      for (int ks = 0; ks < 2; ++ks)                                             \
        bfr[n][ks] = *(const bf16x8*)(lb + row*128 + ((ks*64 + lhi*16) ^ sw));   \
    }                                                                            \
  };                                                                             \
  auto RD_AF = [&](const char* la, int mb, bf16x8 (*af)[2]) {                    \
    _Pragma("unroll")                                                            \
    for (int mm = 0; mm < 2; ++mm) {                                             \
      const int row = wr*64 + (mb + mm)*16 + l15;                                \
      const int sw = (row & 7) << 4;                                             \
      _Pragma("unroll")                                                          \
      for (int ks = 0; ks < 2; ++ks)                                             \
        af[mm][ks] = *(const bf16x8*)(la + row*128 + ((ks*64 + lhi*16) ^ sw));   \
    }                                                                            \
  };                                                                             \
  auto MFMA16 = [&](bf16x8 (*af)[2], bf16x8 (*bfr)[2], int mb) {                 \
    __builtin_amdgcn_s_setprio(1);                                               \
    _Pragma("unroll")                                                            \
    for (int mm = 0; mm < 2; ++mm)                                               \
      _Pragma("unroll")                                                          \
      for (int n = 0; n < 4; ++n)                                                \
        _Pragma("unroll")                                                        \
        for (int ks = 0; ks < 2; ++ks)                                           \
          acc[mb + mm][n] = mfma_bf16(af[mm][ks], bfr[n][ks], acc[mb + mm][n]);  \
    __builtin_amdgcn_s_setprio(0);                                               \
  };                                                                             \
  STAGE_B(0, (char*)lB[0]); STAGE_A(0, (char*)lA[0]); STAGE_B(1, (char*)lB[1]);  \
  asm volatile("s_waitcnt vmcnt(4)" ::: "memory");                               \
  __builtin_amdgcn_s_barrier();                                                  \
  _Pragma("unroll")                                                              \
  for (int it = 0; it < (N_TILES)/2; ++it) {                                     \
    const int t0 = it*2;                                                         \
    bf16x8 bfr[4][2], af[2][2];                                                  \
    RD_BFR((const char*)lB[0], bfr);                                             \
    RD_AF((const char*)lA[0], 0, af);                                            \
    STAGE_A(t0 + 1, (char*)lA[1]);                                               \
    __builtin_amdgcn_s_barrier();                                                \
    MFMA16(af, bfr, 0);                                                          \
    __builtin_amdgcn_s_barrier();                                                \
    RD_AF((const char*)lA[0], 2, af);                                            \
    if (t0 + 2 < (N_TILES)) STAGE_B(t0 + 2, (char*)lB[0]);                       \
    __builtin_amdgcn_s_barrier();                                                \
    MFMA16(af, bfr, 2);                                                          \
    if (t0 + 2 < (N_TILES)) asm volatile("s_waitcnt vmcnt(4)" ::: "memory");     \
    else                    asm volatile("s_waitcnt vmcnt(0)" ::: "memory");     \
    __builtin_amdgcn_s_barrier();                                                \
    RD_BFR((const char*)lB[1], bfr);                                             \
    RD_AF((const char*)lA[1], 0, af);                                            \
    if (t0 + 2 < (N_TILES)) STAGE_A(t0 + 2, (char*)lA[0]);                       \
    __builtin_amdgcn_s_barrier();                                                \
    MFMA16(af, bfr, 0);                                                          \
    __builtin_amdgcn_s_barrier();                                                \
    RD_AF((const char*)lA[1], 2, af);                                            \
    if (t0 + 3 < (N_TILES)) STAGE_B(t0 + 3, (char*)lB[1]);                       \
    __builtin_amdgcn_s_barrier();                                                \
    MFMA16(af, bfr, 2);                                                          \
    if (it < (N_TILES)/2 - 1) asm volatile("s_waitcnt vmcnt(4)" ::: "memory");   \
    __builtin_amdgcn_s_barrier();                                                \
  }

__global__ void __launch_bounds__(512, 2)
gemm_qkv_p(const __bf16* __restrict__ A, const __bf16* __restrict__ Bt,
           __bf16* __restrict__ qout, __bf16* __restrict__ kout, __bf16* __restrict__ vtout,
           const float* __restrict__ cosT, const float* __restrict__ sinT)
{
  __shared__ __attribute__((aligned(16))) char smem[98304];     // 96 KB pool
  auto lA = (__bf16 (*)[128*64])smem;                           // 2 x 16 KB
  auto lB = (__bf16 (*)[256*64])(smem + 32768);                 // 2 x 32 KB
  const int tid = threadIdx.x;
  const int lane = tid & 63, wave = tid >> 6;
  const int wr = wave >> 2, wc = wave & 3;       // 2M x 4N wave grid
  const int l15 = lane & 15, lhi = lane >> 4;

  // M-banded XCD mapping: xcd owns 8 contiguous M-tiles, sweeps N
  const int id = blockIdx.x;                 // 768 blocks
  const int xcd = id & 7, j = id >> 3;       // j in [0,96)
  const int rowt = xcd*8 + (j & 7);          // [0,64)
  const int row0 = rowt * 128;
  const int col0 = (j >> 3) * 256;           // [0,12) * 256

  f32x4 acc[4][4] = {};

  const char* Abase = (const char*)A + (size_t)row0 * 2048;   // K=1024, 2048 B/row
  const char* Bbase = (const char*)Bt + (size_t)col0 * 2048;

  auto STAGE_A = [&](int kt, char* dst) {
    #pragma unroll
    for (int c = 0; c < 2; ++c) {            // A: 128 rows x 128 B = 16 KB
      const int L = tid*16 + c*8192;
      const int row = L >> 7, colb = L & 127;
      const int sb = colb ^ ((row & 7) << 4);   // inverse swizzle on global source
      gload_lds16(Abase + (size_t)row*2048 + kt*128 + sb, dst + L);
    }
  };
  auto STAGE_B = [&](int kt, char* dst) {
    #pragma unroll
    for (int c = 0; c < 4; ++c) {            // B: 256 rows x 128 B = 32 KB
      const int L = tid*16 + c*8192;
      const int row = L >> 7, colb = L & 127;
      const int sb = colb ^ ((row & 7) << 4);
      gload_lds16(Bbase + (size_t)row*2048 + kt*128 + sb, dst + L);
    }
  };

  GEMM_PHASES(16)

  // epilogue: RoPE on q,k (scatter to (B,H,T,D)); V written TRANSPOSED ([bh][d][t]).
  const int slot = (col0 >> 6) + wc;         // 0..47
  const int which = slot >> 4;               // 0=q 1=k 2=v
  const int h = slot & 15;
  if (which == 2) {
    __bf16* lTw = (__bf16*)(smem + wave*8320);   // 64*65*2 B each, 8*8320=66560<=98304
    #pragma unroll
    for (int m = 0; m < 4; ++m)
      #pragma unroll
      for (int r = 0; r < 4; ++r) {
        const int trow = m*16 + lhi*4 + r;   // local t in [0,64)
        #pragma unroll
        for (int n = 0; n < 4; ++n)
          lTw[trow*65 + n*16 + l15] = (__bf16)acc[m][n][r];
      }
    const int t0w = row0 + wr*64;
    const int b = t0w >> 11, tloc = t0w & 2047;
    __bf16* dstv = vtout + ((size_t)(b*H_ + h)*D_)*T_;
    #pragma unroll
    for (int c2 = 0; c2 < 8; ++c2) {
      const int idx = lane + c2*64;
      const int d = idx >> 3, t8 = (idx & 7)*8;
      bf16x8 ov;
      #pragma unroll
      for (int jj = 0; jj < 8; ++jj) ov[jj] = lTw[(t8 + jj)*65 + d];
      *(bf16x8*)(dstv + (size_t)d*T_ + tloc + t8) = ov;
    }
  } else {
    __bf16* dst = (which == 0) ? qout : kout;
    const float fsc = (which == 0) ? 0.18033688011112042f : 1.0f;
    #pragma unroll
    for (int m = 0; m < 4; ++m) {
      #pragma unroll
      for (int r = 0; r < 4; ++r) {
        const int grow = row0 + wr*64 + m*16 + lhi*4 + r;
        const int b = grow >> 11, t = grow & 2047;
        const size_t obase = ((size_t)(b*H_ + h)*T_ + t)*D_;
        #pragma unroll
        for (int n = 0; n < 2; ++n) {
          const int d1 = n*16 + l15;            // [0,32)
          const float c = cosT[t*32 + d1];
          const float s = sinT[t*32 + d1];
          const float x1 = acc[m][n][r];
          const float x2 = acc[m][n+2][r];
          dst[obase + d1]      = (__bf16)((x1*c - x2*s) * fsc);
          dst[obase + d1 + 32] = (__bf16)((x1*s + x2*c) * fsc);
        }
      }
    }
  }
}

// out-proj: same fine-phase structure + M-banded XCD mapping. Grid 256 = 1 round.
__global__ void __launch_bounds__(512, 2)
gemm_out_p(const __bf16* __restrict__ A, const __bf16* __restrict__ Bt,
           float* __restrict__ fout, const float* __restrict__ bias)
{
  __shared__ __attribute__((aligned(16))) __bf16 lA[2][128*64];
  __shared__ __attribute__((aligned(16))) __bf16 lB[2][256*64];
  const int tid = threadIdx.x;
  const int lane = tid & 63, wave = tid >> 6;
  const int wr = wave >> 2, wc = wave & 3;
  const int l15 = lane & 15, lhi = lane >> 4;

  const int id = blockIdx.x;                 // 256 blocks
  const int xcd = id & 7, j = id >> 3;       // j in [0,32)
  const int rowt = xcd*8 + (j & 7);          // [0,64)
  const int row0 = rowt * 128;
  const int col0 = (j >> 3) * 256;           // [0,4) * 256

  f32x4 acc[4][4] = {};

  const char* Abase = (const char*)A + (size_t)row0 * 2048;
  const char* Bbase = (const char*)Bt + (size_t)col0 * 2048;

  auto STAGE_A = [&](int kt, char* dst) {
    #pragma unroll
    for (int c = 0; c < 2; ++c) {
      const int L = tid*16 + c*8192;
      const int row = L >> 7, colb = L & 127;
      const int sb = colb ^ ((row & 7) << 4);
      gload_lds16(Abase + (size_t)row*2048 + kt*128 + sb, dst + L);
    }
  };
  auto STAGE_B = [&](int kt, char* dst) {
    #pragma unroll
    for (int c = 0; c < 4; ++c) {
      const int L = tid*16 + c*8192;
      const int row = L >> 7, colb = L & 127;
      const int sb = colb ^ ((row & 7) << 4);
      gload_lds16(Bbase + (size_t)row*2048 + kt*128 + sb, dst + L);
    }
  };

  GEMM_PHASES(16)

  #pragma unroll
  for (int m = 0; m < 4; ++m) {
    #pragma unroll
    for (int r = 0; r < 4; ++r) {
      const int grow = row0 + wr*64 + m*16 + lhi*4 + r;
      #pragma unroll
      for (int n = 0; n < 4; ++n) {
        const int gcol = col0 + wc*64 + n*16 + l15;
        fout[(size_t)grow*1024 + gcol] = acc[m][n][r] + bias[gcol];
      }
    }
  }
}

// ---------------- flash attention: NO-SPLIT LPT, Q-in-regs, 3 blocks/CU -----------
// Round-19: PSTRIDE = 160 (aligned pad). Round-18's 136 zeroed conflicts but
// broke 16B alignment of the pa b128 reads (row*136 = 8 mod 16 for odd rows ->
// split DS ops, -20us). 160 = 0 mod 16 keeps reads aligned AND rotates banks by
// (l15&3)*32 per row-quadrant -> the b64 P-writes spread ~uniform 4-deep
// (the wave64 minimum) instead of 8-deep-on-half-banks.
#define THR_LOG2 8.0f
#define PSTRIDE 160

__global__ void __launch_bounds__(256, 3)
attn_kernel(const __bf16* __restrict__ q, const __bf16* __restrict__ k,
            const __bf16* __restrict__ vt, const int* __restrict__ amask,
            __bf16* __restrict__ aout)
{
  __shared__ __attribute__((aligned(16))) __bf16 lK[64*64];    // 8 KB
  __shared__ __attribute__((aligned(16))) __bf16 lVt[64*64];   // 8 KB
  __shared__ __attribute__((aligned(16))) __bf16 lP[4][32*80]; // 20 KB (160B rows)
  const int tid = threadIdx.x;
  const int lane = tid & 63, wave = tid >> 6;
  const int l15 = lane & 15, lhi = lane >> 4;

  // heavy-first LPT: blocks 0..63 -> qblock 15 (32 iters), ...
  const int qblock = 15 - (blockIdx.x >> 6);
  const int bh = blockIdx.x & 63;
  const int kbend = 2*qblock + 2;

  const int b = bh >> 4, h = bh & 15;
  const size_t kvbase = (size_t)bh * T_ * D_;
  const char* kbase  = (const char*)(k + kvbase);
  const char* vtbase = (const char*)(vt + kvbase);
  char* lPw = (char*)lP[wave];

  const int q0w = qblock*128 + wave*32;

  // Q fragments in registers (round-0 proven layout)
  bf16x8 aq[2][2];
  #pragma unroll
  for (int m = 0; m < 2; ++m)
    #pragma unroll
    for (int ks = 0; ks < 2; ++ks)
      aq[m][ks] = *(const bf16x8*)(q + kvbase + (size_t)(q0w + m*16 + l15)*D_ + ks*32 + lhi*8);

  f32x4 acc_o[2][4] = {};
  f32x4 acc_l[2] = {};
  float m_w = -3e37f;

  for (int kb = 0; kb < kbend; ++kb) {
    #pragma unroll
    for (int c = 0; c < 2; ++c) {
      const int L = tid*16 + c*4096;
      const int row = L >> 7;
      const int sb  = (L & 127) ^ ((row & 7) << 4);
      gload_lds16(kbase  + (size_t)(kb*64 + row)*128 + sb, (char*)lK + L);
      gload_lds16(vtbase + (size_t)row*(T_*2) + (size_t)kb*128 + sb, (char*)lVt + L);
    }
    __syncthreads();

    if (kb*64 <= q0w + 31) {
      const char* lKc = (const char*)lK;
      const char* lVc = (const char*)lVt;

      // pad-mask bits for this k-tile: bit i = amask[kb*64+i] != 0
      const unsigned long long pm = __ballot(amask[b*T_ + kb*64 + lane] != 0);

      // SWAPPED QK^T: sc[m][n] = mfma(K_frag, Q_frag)
      //   value S[q][k]: q = q0w + m*16 + l15 ; k = kb*64 + n*16 + lhi*4 + r
      f32x4 sc[2][4] = {};
      __builtin_amdgcn_s_setprio(1);
      #pragma unroll
      for (int n = 0; n < 4; ++n) {
        const int row = n*16 + l15;
        const int sw = (row & 7) << 4;
        #pragma unroll
        for (int ks = 0; ks < 2; ++ks) {
          bf16x8 bk = *(const bf16x8*)(lKc + row*128 + ((ks*64 + lhi*16) ^ sw));
          #pragma unroll
          for (int m = 0; m < 2; ++m)
            sc[m][n] = mfma_bf16(bk, aq[m][ks], sc[m][n]);
        }
      }
      __builtin_amdgcn_s_setprio(0);

      // causal mask (swapped indices)
      if (kb*64 + 63 > q0w) {
        #pragma unroll
        for (int m = 0; m < 2; ++m) {
          const int qv = q0w + m*16 + l15;
          #pragma unroll
          for (int n = 0; n < 4; ++n)
            #pragma unroll
            for (int r = 0; r < 4; ++r)
              if (kb*64 + n*16 + lhi*4 + r > qv) sc[m][n][r] = -3e37f;
        }
      }

      f32x4 vm = sc[0][0];
      #pragma unroll
      for (int m = 0; m < 2; ++m)
        #pragma unroll
        for (int n = 0; n < 4; ++n) {
          if (m == 0 && n == 0) continue;
          #pragma unroll
          for (int r = 0; r < 4; ++r) vm[r] = fmaxf(vm[r], sc[m][n][r]);
        }
      float tmax = fmaxf(fmaxf(vm[0], vm[1]), fmaxf(vm[2], vm[3]));
      #pragma unroll
      for (int off = 1; off < 64; off <<= 1)
        tmax = fmaxf(tmax, __shfl_xor(tmax, off));

      if (tmax > m_w + THR_LOG2) {
        const float corr = __builtin_amdgcn_exp2f(m_w - tmax);
        #pragma unroll
        for (int m = 0; m < 2; ++m) {
          #pragma unroll
          for (int c = 0; c < 4; ++c) acc_o[m][c] *= corr;
          acc_l[m] *= corr;
        }
        m_w = tmax;
      }

      // P pack + vector write: row = m*16 + l15 (q-row), 4 contiguous k per (n)
      const int swq = (l15 & 7) << 4;
      if (pm == ~0ull) {
        // fast path: all k valid -> subtrahend is m_w everywhere
        #pragma unroll
        for (int m = 0; m < 2; ++m) {
          char* prow = lPw + (m*16 + l15)*PSTRIDE;
          #pragma unroll
          for (int n = 0; n < 4; ++n) {
            bf16x4 pk;
            #pragma unroll
            for (int r = 0; r < 4; ++r)
              pk[r] = (__bf16)__builtin_amdgcn_exp2f(sc[m][n][r] - m_w);
            *(bf16x4*)(prow + ((32*n + 8*lhi) ^ swq)) = pk;
          }
        }
      } else {
        #pragma unroll
        for (int m = 0; m < 2; ++m) {
          char* prow = lPw + (m*16 + l15)*PSTRIDE;
          #pragma unroll
          for (int n = 0; n < 4; ++n) {
            bf16x4 pk;
            #pragma unroll
            for (int r = 0; r < 4; ++r) {
              const float sub = ((pm >> (n*16 + lhi*4 + r)) & 1) ? m_w : 3e37f;
              pk[r] = (__bf16)__builtin_amdgcn_exp2f(sc[m][n][r] - sub);
            }
            *(bf16x4*)(prow + ((32*n + 8*lhi) ^ swq)) = pk;
          }
        }
      }

      bf16x8 pa[2][2];
      #pragma unroll
      for (int m = 0; m < 2; ++m) {
        const int row = m*16 + l15;
        const int sw = (row & 7) << 4;
        #pragma unroll
        for (int ks = 0; ks < 2; ++ks)
          pa[m][ks] = *(const bf16x8*)(lPw + row*PSTRIDE + ((ks*64 + lhi*16) ^ sw));
      }

      __builtin_amdgcn_s_setprio(1);
      const __bf16 one = (__bf16)1.0f;
      const bf16x8 vone = {one, one, one, one, one, one, one, one};
      #pragma unroll
      for (int m = 0; m < 2; ++m)
        #pragma unroll
        for (int ks = 0; ks < 2; ++ks)
          acc_l[m] = mfma_bf16(pa[m][ks], vone, acc_l[m]);

      #pragma unroll
      for (int c = 0; c < 4; ++c) {
        const int row = c*16 + l15;
        const int sw = (row & 7) << 4;
        #pragma unroll
        for (int ks = 0; ks < 2; ++ks) {
          bf16x8 bv = *(const bf16x8*)(lVc + row*128 + ((ks*64 + lhi*16) ^ sw));
          #pragma unroll
          for (int m = 0; m < 2; ++m)
            acc_o[m][c] = mfma_bf16(pa[m][ks], bv, acc_o[m][c]);
        }
      }
      __builtin_amdgcn_s_setprio(0);
    }
    __syncthreads();
  }

  // normalize and write
  #pragma unroll
  for (int m = 0; m < 2; ++m)
    #pragma unroll
    for (int r = 0; r < 4; ++r) {
      const int tq = q0w + m*16 + lhi*4 + r;
      const float invl = 1.0f / acc_l[m][r];
      const size_t obase = ((size_t)b*T_ + tq)*C_ + h*D_;
      #pragma unroll
      for (int c = 0; c < 4; ++c)
        aout[obase + c*16 + l15] = (__bf16)(acc_o[m][c][r] * invl);
    }
}

// ---------------- launch ----------------

extern "C" void kernel_launch(void* const* d_in, const int* in_sizes, int n_in,
                              void* d_out, int out_size, void* d_ws, size_t ws_size,
                              hipStream_t stream)
{
  const float* x     = (const float*)d_in[0];
  const int*   amask = (const int*)d_in[1];
  const float* Wqkv  = (const float*)d_in[2];
  const float* Wout  = (const float*)d_in[3];
  const float* bout  = (const float*)d_in[4];
  float* out = (float*)d_out;

  char* w = (char*)d_ws;
  __bf16* xb    = (__bf16*)w;  w += (size_t)M_TOT*C_*2;       // 16 MB
  __bf16* wqkvT = (__bf16*)w;  w += (size_t)3072*1024*2;      // 6 MB
  __bf16* woutT = (__bf16*)w;  w += (size_t)1024*1024*2;      // 2 MB
  __bf16* qb    = (__bf16*)w;  w += (size_t)B_*H_*T_*D_*2;    // 16 MB
  __bf16* kb    = (__bf16*)w;  w += (size_t)B_*H_*T_*D_*2;    // 16 MB
  __bf16* vtb   = (__bf16*)w;  w += (size_t)B_*H_*T_*D_*2;    // 16 MB  (V^T, written by gemm)
  __bf16* aob   = (__bf16*)w;  w += (size_t)M_TOT*C_*2;       // 16 MB
  float*  cosT  = (float*)w;   w += (size_t)T_*32*4;
  float*  sinT  = (float*)w;   w += (size_t)T_*32*4;

  prep_all<<<dim3(8192 + 256 + 3072 + 1024), 256, 0, stream>>>(
      x, xb, cosT, sinT, Wqkv, wqkvT, Wout, woutT);

  gemm_qkv_p<<<dim3(768), 512, 0, stream>>>(xb, wqkvT, qb, kb, vtb, cosT, sinT);

  attn_kernel<<<dim3(1024), 256, 0, stream>>>(qb, kb, vtb, amask, aob);

  gemm_out_p<<<dim3(256), 512, 0, stream>>>(aob, woutT, out, bout);
}

// Round 20
// 162.334 us; speedup vs baseline: 1.1193x; 1.0075x over previous
//
#include <hip/hip_runtime.h>
#include <hip/hip_bf16.h>
#include <math.h>

typedef __attribute__((ext_vector_type(8))) __bf16 bf16x8;
typedef __attribute__((ext_vector_type(4))) __bf16 bf16x4;
typedef __attribute__((ext_vector_type(4))) float f32x4;

#define B_ 4
#define T_ 2048
#define C_ 1024
#define H_ 16
#define D_ 64
#define M_TOT (B_*T_)

static __device__ __forceinline__ f32x4 mfma_bf16(bf16x8 a, bf16x8 b, f32x4 c) {
  return __builtin_amdgcn_mfma_f32_16x16x32_bf16(a, b, c, 0, 0, 0);
}

static __device__ __forceinline__ void gload_lds16(const void* g, void* l) {
  __builtin_amdgcn_global_load_lds((const __attribute__((address_space(1))) void*)g,
                                   (__attribute__((address_space(3))) void*)l, 16, 0, 0);
}

// ---------------- fused prep: convert + rope tables + both weight transposes -------
__global__ void prep_all(const float* __restrict__ x, __bf16* __restrict__ xb,
                         float* __restrict__ cosT, float* __restrict__ sinT,
                         const float* __restrict__ Wqkv, __bf16* __restrict__ wqkvT,
                         const float* __restrict__ Wout, __bf16* __restrict__ woutT) {
  __shared__ float tile[32][33];
  const int bid = blockIdx.x;
  if (bid < 8192) {
    int i = bid * 256 + threadIdx.x;       // n4 = M_TOT*C_/4 = 2097152 = 8192*256
    float4 v = ((const float4*)x)[i];
    bf16x4 o = { (__bf16)v.x, (__bf16)v.y, (__bf16)v.z, (__bf16)v.w };
    *(bf16x4*)(xb + (size_t)i*4) = o;
  } else if (bid < 8448) {
    int idx = (bid - 8192) * 256 + threadIdx.x;   // T_*32 = 65536 = 256*256
    int t = idx >> 5, d = idx & 31;
    float inv = powf(10000.0f, -((float)(2*d)) / 64.0f);
    float ang = (float)t * inv;
    cosT[idx] = cosf(ang);
    sinT[idx] = sinf(ang);
  } else {
    int tId = bid - 8448;
    const float* in;  __bf16* out;  int N, n0, k0;
    if (tId < 3072) { in = Wqkv; out = wqkvT; N = 3072; n0 = (tId % 96)*32; k0 = (tId / 96)*32; }
    else { tId -= 3072; in = Wout; out = woutT; N = 1024; n0 = (tId % 32)*32; k0 = (tId / 32)*32; }
    int tx = threadIdx.x & 31, ty = threadIdx.x >> 5;
    #pragma unroll
    for (int r = ty; r < 32; r += 8) tile[r][tx] = in[(size_t)(k0 + r)*N + n0 + tx];
    __syncthreads();
    #pragma unroll
    for (int r = ty; r < 32; r += 8) out[(size_t)(n0 + r)*1024 + k0 + tx] = (__bf16)tile[tx][r];
  }
}

// ---------------- fine-phase pipelined GEMM: 128x256 tile, BK=64, 8 waves -----------
// Round-8 proven structure: M-banded XCD mapping, 4 phases per 2-K-tile iteration,
// counted vmcnt(4), raw s_barrier. V^T written from the epilogue via per-wave
// transpose buffers (pad 65: row stride 130B kills the 8-way column-read conflict).

#define GEMM_PHASES(N_TILES)                                                     \
  auto RD_BFR = [&](const char* lb, bf16x8 (*bfr)[2]) {                          \
    _Pragma("unroll")                                                            \
    for (int n = 0; n < 4; ++n) {                                                \
      const int row = wc*64 + n*16 + l15;                                        \
      const int sw = (row & 7) << 4;                                             \
      _Pragma("unroll")                                                          \
      for (int ks = 0; ks < 2; ++ks)                                             \
        bfr[n][ks] = *(const bf16x8*)(lb + row*128 + ((ks*64 + lhi*16) ^ sw));   \
    }                                                                            \
  };                                                                             \
  auto RD_AF = [&](const char* la, int mb, bf16x8 (*af)[2]) {                    \
    _Pragma("unroll")                                                            \
    for (int mm = 0; mm < 2; ++mm) {                                             \
      const int row = wr*64 + (mb + mm)*16 + l15;                                \
      const int sw = (row & 7) << 4;                                             \
      _Pragma("unroll")                                                          \
      for (int ks = 0; ks < 2; ++ks)                                             \
        af[mm][ks] = *(const bf16x8*)(la + row*128 + ((ks*64 + lhi*16) ^ sw));   \
    }                                                                            \
  };                                                                             \
  auto MFMA16 = [&](bf16x8 (*af)[2], bf16x8 (*bfr)[2], int mb) {                 \
    __builtin_amdgcn_s_setprio(1);                                               \
    _Pragma("unroll")                                                            \
    for (int mm = 0; mm < 2; ++mm)                                               \
      _Pragma("unroll")                                                          \
      for (int n = 0; n < 4; ++n)                                                \
        _Pragma("unroll")                                                        \
        for (int ks = 0; ks < 2; ++ks)                                           \
          acc[mb + mm][n] = mfma_bf16(af[mm][ks], bfr[n][ks], acc[mb + mm][n]);  \
    __builtin_amdgcn_s_setprio(0);                                               \
  };                                                                             \
  STAGE_B(0, (char*)lB[0]); STAGE_A(0, (char*)lA[0]); STAGE_B(1, (char*)lB[1]);  \
  asm volatile("s_waitcnt vmcnt(4)" ::: "memory");                               \
  __builtin_amdgcn_s_barrier();                                                  \
  _Pragma("unroll")                                                              \
  for (int it = 0; it < (N_TILES)/2; ++it) {                                     \
    const int t0 = it*2;                                                         \
    bf16x8 bfr[4][2], af[2][2];                                                  \
    RD_BFR((const char*)lB[0], bfr);                                             \
    RD_AF((const char*)lA[0], 0, af);                                            \
    STAGE_A(t0 + 1, (char*)lA[1]);                                               \
    __builtin_amdgcn_s_barrier();                                                \
    MFMA16(af, bfr, 0);                                                          \
    __builtin_amdgcn_s_barrier();                                                \
    RD_AF((const char*)lA[0], 2, af);                                            \
    if (t0 + 2 < (N_TILES)) STAGE_B(t0 + 2, (char*)lB[0]);                       \
    __builtin_amdgcn_s_barrier();                                                \
    MFMA16(af, bfr, 2);                                                          \
    if (t0 + 2 < (N_TILES)) asm volatile("s_waitcnt vmcnt(4)" ::: "memory");     \
    else                    asm volatile("s_waitcnt vmcnt(0)" ::: "memory");     \
    __builtin_amdgcn_s_barrier();                                                \
    RD_BFR((const char*)lB[1], bfr);                                             \
    RD_AF((const char*)lA[1], 0, af);                                            \
    if (t0 + 2 < (N_TILES)) STAGE_A(t0 + 2, (char*)lA[0]);                       \
    __builtin_amdgcn_s_barrier();                                                \
    MFMA16(af, bfr, 0);                                                          \
    __builtin_amdgcn_s_barrier();                                                \
    RD_AF((const char*)lA[1], 2, af);                                            \
    if (t0 + 3 < (N_TILES)) STAGE_B(t0 + 3, (char*)lB[1]);                       \
    __builtin_amdgcn_s_barrier();                                                \
    MFMA16(af, bfr, 2);                                                          \
    if (it < (N_TILES)/2 - 1) asm volatile("s_waitcnt vmcnt(4)" ::: "memory");   \
    __builtin_amdgcn_s_barrier();                                                \
  }

__global__ void __launch_bounds__(512, 2)
gemm_qkv_p(const __bf16* __restrict__ A, const __bf16* __restrict__ Bt,
           __bf16* __restrict__ qout, __bf16* __restrict__ kout, __bf16* __restrict__ vtout,
           const float* __restrict__ cosT, const float* __restrict__ sinT)
{
  __shared__ __attribute__((aligned(16))) char smem[98304];     // 96 KB pool
  auto lA = (__bf16 (*)[128*64])smem;                           // 2 x 16 KB
  auto lB = (__bf16 (*)[256*64])(smem + 32768);                 // 2 x 32 KB
  const int tid = threadIdx.x;
  const int lane = tid & 63, wave = tid >> 6;
  const int wr = wave >> 2, wc = wave & 3;       // 2M x 4N wave grid
  const int l15 = lane & 15, lhi = lane >> 4;

  // M-banded XCD mapping: xcd owns 8 contiguous M-tiles, sweeps N
  const int id = blockIdx.x;                 // 768 blocks
  const int xcd = id & 7, j = id >> 3;       // j in [0,96)
  const int rowt = xcd*8 + (j & 7);          // [0,64)
  const int row0 = rowt * 128;
  const int col0 = (j >> 3) * 256;           // [0,12) * 256

  f32x4 acc[4][4] = {};

  const char* Abase = (const char*)A + (size_t)row0 * 2048;   // K=1024, 2048 B/row
  const char* Bbase = (const char*)Bt + (size_t)col0 * 2048;

  auto STAGE_A = [&](int kt, char* dst) {
    #pragma unroll
    for (int c = 0; c < 2; ++c) {            // A: 128 rows x 128 B = 16 KB
      const int L = tid*16 + c*8192;
      const int row = L >> 7, colb = L & 127;
      const int sb = colb ^ ((row & 7) << 4);   // inverse swizzle on global source
      gload_lds16(Abase + (size_t)row*2048 + kt*128 + sb, dst + L);
    }
  };
  auto STAGE_B = [&](int kt, char* dst) {
    #pragma unroll
    for (int c = 0; c < 4; ++c) {            // B: 256 rows x 128 B = 32 KB
      const int L = tid*16 + c*8192;
      const int row = L >> 7, colb = L & 127;
      const int sb = colb ^ ((row & 7) << 4);
      gload_lds16(Bbase + (size_t)row*2048 + kt*128 + sb, dst + L);
    }
  };

  GEMM_PHASES(16)

  // epilogue: RoPE on q,k (scatter to (B,H,T,D)); V written TRANSPOSED ([bh][d][t]).
  const int slot = (col0 >> 6) + wc;         // 0..47
  const int which = slot >> 4;               // 0=q 1=k 2=v
  const int h = slot & 15;
  if (which == 2) {
    __bf16* lTw = (__bf16*)(smem + wave*8320);   // 64*65*2 B each, 8*8320=66560<=98304
    #pragma unroll
    for (int m = 0; m < 4; ++m)
      #pragma unroll
      for (int r = 0; r < 4; ++r) {
        const int trow = m*16 + lhi*4 + r;   // local t in [0,64)
        #pragma unroll
        for (int n = 0; n < 4; ++n)
          lTw[trow*65 + n*16 + l15] = (__bf16)acc[m][n][r];
      }
    const int t0w = row0 + wr*64;
    const int b = t0w >> 11, tloc = t0w & 2047;
    __bf16* dstv = vtout + ((size_t)(b*H_ + h)*D_)*T_;
    #pragma unroll
    for (int c2 = 0; c2 < 8; ++c2) {
      const int idx = lane + c2*64;
      const int d = idx >> 3, t8 = (idx & 7)*8;
      bf16x8 ov;
      #pragma unroll
      for (int jj = 0; jj < 8; ++jj) ov[jj] = lTw[(t8 + jj)*65 + d];
      *(bf16x8*)(dstv + (size_t)d*T_ + tloc + t8) = ov;
    }
  } else {
    __bf16* dst = (which == 0) ? qout : kout;
    const float fsc = (which == 0) ? 0.18033688011112042f : 1.0f;
    #pragma unroll
    for (int m = 0; m < 4; ++m) {
      #pragma unroll
      for (int r = 0; r < 4; ++r) {
        const int grow = row0 + wr*64 + m*16 + lhi*4 + r;
        const int b = grow >> 11, t = grow & 2047;
        const size_t obase = ((size_t)(b*H_ + h)*T_ + t)*D_;
        #pragma unroll
        for (int n = 0; n < 2; ++n) {
          const int d1 = n*16 + l15;            // [0,32)
          const float c = cosT[t*32 + d1];
          const float s = sinT[t*32 + d1];
          const float x1 = acc[m][n][r];
          const float x2 = acc[m][n+2][r];
          dst[obase + d1]      = (__bf16)((x1*c - x2*s) * fsc);
          dst[obase + d1 + 32] = (__bf16)((x1*s + x2*c) * fsc);
        }
      }
    }
  }
}

// out-proj: same fine-phase structure + M-banded XCD mapping. Grid 256 = 1 round.
__global__ void __launch_bounds__(512, 2)
gemm_out_p(const __bf16* __restrict__ A, const __bf16* __restrict__ Bt,
           float* __restrict__ fout, const float* __restrict__ bias)
{
  __shared__ __attribute__((aligned(16))) __bf16 lA[2][128*64];
  __shared__ __attribute__((aligned(16))) __bf16 lB[2][256*64];
  const int tid = threadIdx.x;
  const int lane = tid & 63, wave = tid >> 6;
  const int wr = wave >> 2, wc = wave & 3;
  const int l15 = lane & 15, lhi = lane >> 4;

  const int id = blockIdx.x;                 // 256 blocks
  const int xcd = id & 7, j = id >> 3;       // j in [0,32)
  const int rowt = xcd*8 + (j & 7);          // [0,64)
  const int row0 = rowt * 128;
  const int col0 = (j >> 3) * 256;           // [0,4) * 256

  f32x4 acc[4][4] = {};

  const char* Abase = (const char*)A + (size_t)row0 * 2048;
  const char* Bbase = (const char*)Bt + (size_t)col0 * 2048;

  auto STAGE_A = [&](int kt, char* dst) {
    #pragma unroll
    for (int c = 0; c < 2; ++c) {
      const int L = tid*16 + c*8192;
      const int row = L >> 7, colb = L & 127;
      const int sb = colb ^ ((row & 7) << 4);
      gload_lds16(Abase + (size_t)row*2048 + kt*128 + sb, dst + L);
    }
  };
  auto STAGE_B = [&](int kt, char* dst) {
    #pragma unroll
    for (int c = 0; c < 4; ++c) {
      const int L = tid*16 + c*8192;
      const int row = L >> 7, colb = L & 127;
      const int sb = colb ^ ((row & 7) << 4);
      gload_lds16(Bbase + (size_t)row*2048 + kt*128 + sb, dst + L);
    }
  };

  GEMM_PHASES(16)

  #pragma unroll
  for (int m = 0; m < 4; ++m) {
    #pragma unroll
    for (int r = 0; r < 4; ++r) {
      const int grow = row0 + wr*64 + m*16 + lhi*4 + r;
      #pragma unroll
      for (int n = 0; n < 4; ++n) {
        const int gcol = col0 + wc*64 + n*16 + l15;
        fout[(size_t)grow*1024 + gcol] = acc[m][n][r] + bias[gcol];
      }
    }
  }
}

// ---------------- flash attention: NO-SPLIT LPT, Q-in-regs, 3 blocks/CU -----------
// Round-17 best configuration (162.9us total), restored after the PSTRIDE
// experiments: 136 broke b128 read alignment (-20us); 160 worsened banks.
// The 128-B lP rows' ~4-way b64 write conflict costs <1us under TLP — not a lever.
#define THR_LOG2 8.0f

__global__ void __launch_bounds__(256, 3)
attn_kernel(const __bf16* __restrict__ q, const __bf16* __restrict__ k,
            const __bf16* __restrict__ vt, const int* __restrict__ amask,
            __bf16* __restrict__ aout)
{
  __shared__ __attribute__((aligned(16))) __bf16 lK[64*64];    // 8 KB
  __shared__ __attribute__((aligned(16))) __bf16 lVt[64*64];   // 8 KB
  __shared__ __attribute__((aligned(16))) __bf16 lP[4][32*64]; // 16 KB
  const int tid = threadIdx.x;
  const int lane = tid & 63, wave = tid >> 6;
  const int l15 = lane & 15, lhi = lane >> 4;

  // heavy-first LPT: blocks 0..63 -> qblock 15 (32 iters), ...
  const int qblock = 15 - (blockIdx.x >> 6);
  const int bh = blockIdx.x & 63;
  const int kbend = 2*qblock + 2;

  const int b = bh >> 4, h = bh & 15;
  const size_t kvbase = (size_t)bh * T_ * D_;
  const char* kbase  = (const char*)(k + kvbase);
  const char* vtbase = (const char*)(vt + kvbase);
  char* lPw = (char*)lP[wave];

  const int q0w = qblock*128 + wave*32;

  // Q fragments in registers (round-0 proven layout)
  bf16x8 aq[2][2];
  #pragma unroll
  for (int m = 0; m < 2; ++m)
    #pragma unroll
    for (int ks = 0; ks < 2; ++ks)
      aq[m][ks] = *(const bf16x8*)(q + kvbase + (size_t)(q0w + m*16 + l15)*D_ + ks*32 + lhi*8);

  f32x4 acc_o[2][4] = {};
  f32x4 acc_l[2] = {};
  float m_w = -3e37f;

  for (int kb = 0; kb < kbend; ++kb) {
    #pragma unroll
    for (int c = 0; c < 2; ++c) {
      const int L = tid*16 + c*4096;
      const int row = L >> 7;
      const int sb  = (L & 127) ^ ((row & 7) << 4);
      gload_lds16(kbase  + (size_t)(kb*64 + row)*128 + sb, (char*)lK + L);
      gload_lds16(vtbase + (size_t)row*(T_*2) + (size_t)kb*128 + sb, (char*)lVt + L);
    }
    __syncthreads();

    if (kb*64 <= q0w + 31) {
      const char* lKc = (const char*)lK;
      const char* lVc = (const char*)lVt;

      // pad-mask bits for this k-tile: bit i = amask[kb*64+i] != 0
      const unsigned long long pm = __ballot(amask[b*T_ + kb*64 + lane] != 0);

      // SWAPPED QK^T: sc[m][n] = mfma(K_frag, Q_frag)
      //   value S[q][k]: q = q0w + m*16 + l15 ; k = kb*64 + n*16 + lhi*4 + r
      f32x4 sc[2][4] = {};
      __builtin_amdgcn_s_setprio(1);
      #pragma unroll
      for (int n = 0; n < 4; ++n) {
        const int row = n*16 + l15;
        const int sw = (row & 7) << 4;
        #pragma unroll
        for (int ks = 0; ks < 2; ++ks) {
          bf16x8 bk = *(const bf16x8*)(lKc + row*128 + ((ks*64 + lhi*16) ^ sw));
          #pragma unroll
          for (int m = 0; m < 2; ++m)
            sc[m][n] = mfma_bf16(bk, aq[m][ks], sc[m][n]);
        }
      }
      __builtin_amdgcn_s_setprio(0);

      // causal mask (swapped indices)
      if (kb*64 + 63 > q0w) {
        #pragma unroll
        for (int m = 0; m < 2; ++m) {
          const int qv = q0w + m*16 + l15;
          #pragma unroll
          for (int n = 0; n < 4; ++n)
            #pragma unroll
            for (int r = 0; r < 4; ++r)
              if (kb*64 + n*16 + lhi*4 + r > qv) sc[m][n][r] = -3e37f;
        }
      }

      f32x4 vm = sc[0][0];
      #pragma unroll
      for (int m = 0; m < 2; ++m)
        #pragma unroll
        for (int n = 0; n < 4; ++n) {
          if (m == 0 && n == 0) continue;
          #pragma unroll
          for (int r = 0; r < 4; ++r) vm[r] = fmaxf(vm[r], sc[m][n][r]);
        }
      float tmax = fmaxf(fmaxf(vm[0], vm[1]), fmaxf(vm[2], vm[3]));
      #pragma unroll
      for (int off = 1; off < 64; off <<= 1)
        tmax = fmaxf(tmax, __shfl_xor(tmax, off));

      if (tmax > m_w + THR_LOG2) {
        const float corr = __builtin_amdgcn_exp2f(m_w - tmax);
        #pragma unroll
        for (int m = 0; m < 2; ++m) {
          #pragma unroll
          for (int c = 0; c < 4; ++c) acc_o[m][c] *= corr;
          acc_l[m] *= corr;
        }
        m_w = tmax;
      }

      // P pack + vector write: row = m*16 + l15 (q-row), 4 contiguous k per (n)
      const int swq = (l15 & 7) << 4;
      if (pm == ~0ull) {
        // fast path: all k valid -> subtrahend is m_w everywhere
        #pragma unroll
        for (int m = 0; m < 2; ++m) {
          char* prow = lPw + (m*16 + l15)*128;
          #pragma unroll
          for (int n = 0; n < 4; ++n) {
            bf16x4 pk;
            #pragma unroll
            for (int r = 0; r < 4; ++r)
              pk[r] = (__bf16)__builtin_amdgcn_exp2f(sc[m][n][r] - m_w);
            *(bf16x4*)(prow + ((32*n + 8*lhi) ^ swq)) = pk;
          }
        }
      } else {
        #pragma unroll
        for (int m = 0; m < 2; ++m) {
          char* prow = lPw + (m*16 + l15)*128;
          #pragma unroll
          for (int n = 0; n < 4; ++n) {
            bf16x4 pk;
            #pragma unroll
            for (int r = 0; r < 4; ++r) {
              const float sub = ((pm >> (n*16 + lhi*4 + r)) & 1) ? m_w : 3e37f;
              pk[r] = (__bf16)__builtin_amdgcn_exp2f(sc[m][n][r] - sub);
            }
            *(bf16x4*)(prow + ((32*n + 8*lhi) ^ swq)) = pk;
          }
        }
      }

      bf16x8 pa[2][2];
      #pragma unroll
      for (int m = 0; m < 2; ++m) {
        const int row = m*16 + l15;
        const int sw = (row & 7) << 4;
        #pragma unroll
        for (int ks = 0; ks < 2; ++ks)
          pa[m][ks] = *(const bf16x8*)(lPw + row*128 + ((ks*64 + lhi*16) ^ sw));
      }

      __builtin_amdgcn_s_setprio(1);
      const __bf16 one = (__bf16)1.0f;
      const bf16x8 vone = {one, one, one, one, one, one, one, one};
      #pragma unroll
      for (int m = 0; m < 2; ++m)
        #pragma unroll
        for (int ks = 0; ks < 2; ++ks)
          acc_l[m] = mfma_bf16(pa[m][ks], vone, acc_l[m]);

      #pragma unroll
      for (int c = 0; c < 4; ++c) {
        const int row = c*16 + l15;
        const int sw = (row & 7) << 4;
        #pragma unroll
        for (int ks = 0; ks < 2; ++ks) {
          bf16x8 bv = *(const bf16x8*)(lVc + row*128 + ((ks*64 + lhi*16) ^ sw));
          #pragma unroll
          for (int m = 0; m < 2; ++m)
            acc_o[m][c] = mfma_bf16(pa[m][ks], bv, acc_o[m][c]);
        }
      }
      __builtin_amdgcn_s_setprio(0);
    }
    __syncthreads();
  }

  // normalize and write
  #pragma unroll
  for (int m = 0; m < 2; ++m)
    #pragma unroll
    for (int r = 0; r < 4; ++r) {
      const int tq = q0w + m*16 + lhi*4 + r;
      const float invl = 1.0f / acc_l[m][r];
      const size_t obase = ((size_t)b*T_ + tq)*C_ + h*D_;
      #pragma unroll
      for (int c = 0; c < 4; ++c)
        aout[obase + c*16 + l15] = (__bf16)(acc_o[m][c][r] * invl);
    }
}

// ---------------- launch ----------------

extern "C" void kernel_launch(void* const* d_in, const int* in_sizes, int n_in,
                              void* d_out, int out_size, void* d_ws, size_t ws_size,
                              hipStream_t stream)
{
  const float* x     = (const float*)d_in[0];
  const int*   amask = (const int*)d_in[1];
  const float* Wqkv  = (const float*)d_in[2];
  const float* Wout  = (const float*)d_in[3];
  const float* bout  = (const float*)d_in[4];
  float* out = (float*)d_out;

  char* w = (char*)d_ws;
  __bf16* xb    = (__bf16*)w;  w += (size_t)M_TOT*C_*2;       // 16 MB
  __bf16* wqkvT = (__bf16*)w;  w += (size_t)3072*1024*2;      // 6 MB
  __bf16* woutT = (__bf16*)w;  w += (size_t)1024*1024*2;      // 2 MB
  __bf16* qb    = (__bf16*)w;  w += (size_t)B_*H_*T_*D_*2;    // 16 MB
  __bf16* kb    = (__bf16*)w;  w += (size_t)B_*H_*T_*D_*2;    // 16 MB
  __bf16* vtb   = (__bf16*)w;  w += (size_t)B_*H_*T_*D_*2;    // 16 MB  (V^T, written by gemm)
  __bf16* aob   = (__bf16*)w;  w += (size_t)M_TOT*C_*2;       // 16 MB
  float*  cosT  = (float*)w;   w += (size_t)T_*32*4;
  float*  sinT  = (float*)w;   w += (size_t)T_*32*4;

  prep_all<<<dim3(8192 + 256 + 3072 + 1024), 256, 0, stream>>>(
      x, xb, cosT, sinT, Wqkv, wqkvT, Wout, woutT);

  gemm_qkv_p<<<dim3(768), 512, 0, stream>>>(xb, wqkvT, qb, kb, vtb, cosT, sinT);

  attn_kernel<<<dim3(1024), 256, 0, stream>>>(qb, kb, vtb, amask, aob);

  gemm_out_p<<<dim3(256), 512, 0, stream>>>(aob, woutT, out, bout);
}